// Round 7
// baseline (179.246 us; speedup 1.0000x reference)
//
#include <hip/hip_runtime.h>
#include <hip/hip_cooperative_groups.h>

namespace cg = cooperative_groups;

#define DEVI __device__ __forceinline__

constexpr int N_ = 2, C_ = 80, H_ = 32, W_ = 40, HW_ = H_ * W_, HWC_ = HW_ * C_;
constexpr int KTOP = 1000, M2_ = 196;
constexpr int IMH = 256, IMW = 320;
constexpr int NB = 2048;          // f32-derived bins
constexpr int KB = 16;            // slices per image
constexpr int SLICE = HWC_ / KB;  // 6400 = 5*HW_
constexpr int BCAP = 2048;        // gathered-candidate cap (expected G ~ 1060)
constexpr int GBLK = 200;         // cooperative grid

// output layout (floats): bx[2][100][4] | sc[2][100] | lb[2][100] | prob[2][100][196] | vf[2][100]
constexpr int O_SC = 800, O_LB = 1000, O_PB = 1200, O_VF = 40400;

DEVI unsigned long long mapd(double v) {
  unsigned long long u = (unsigned long long)__double_as_longlong(v);
  return (u & 0x8000000000000000ull) ? ~u : (u | 0x8000000000000000ull);
}
DEVI double unmapd(unsigned long long k) {
  unsigned long long u = (k & 0x8000000000000000ull) ? (k ^ 0x8000000000000000ull) : ~k;
  return __longlong_as_double((long long)u);
}
DEVI int i0of(int x, int cap) {  // exact first contributing mask row/col (matches table arithmetic)
  float src = ((float)x + 0.5f) * 0.125f - 0.5f;
  src = fminf(fmaxf(src, 0.f), (float)cap);
  return (int)floorf(src);
}

struct ShSlice {  // phases A+B (slice blocks). key[] persists across grid.sync (block stays resident)
  unsigned key[SLICE];
  unsigned hist[NB];
  float ce[HW_];
  unsigned wtot[16], wabove[16], sliceCnt[16], sliceOff[17];
  unsigned sD, lcnt;
};
struct ShSort { unsigned long long K[BCAP]; unsigned I[BCAP]; };
struct ShNms  { double bx[128][5]; unsigned short ml[128]; };
struct ShMask { float tile[4][32][33]; };
struct ShFin  { int lsel[100], lvf[100]; unsigned wcnt[16], woff[16], Stot; float A[H_], Bw[W_]; };
union ShU { ShSlice a; ShSort c; ShNms d; ShMask m; ShFin e; };

__global__ __launch_bounds__(1024) void mega(const float* cls, const float* cent, const float* bm,
                                             const float* loc, const float* breg,
                                             unsigned* ghist, unsigned* bufI, unsigned* cntG,
                                             double* bxd, double* scd, int* lab, int* vld, int* rg,
                                             unsigned* keepg, float* msig, float* wr, float* wc,
                                             float* out) {
  __shared__ ShU sh;
  cg::grid_group gg = cg::this_grid();
  int b = blockIdx.x, tid = threadIdx.x, lane = tid & 63, wid = tid >> 6;

  // ================= Phase A: f32 scores + hist (LDS-resident keys) | mask | tables =================
  if (b < N_ * KB) {
    int n = b >> 4, sb = b & 15;
    size_t base = (size_t)n * HWC_ + (size_t)sb * SLICE;
    for (int j = tid; j < NB; j += 1024) sh.a.hist[j] = 0;
    for (int j = tid; j < HW_; j += 1024) sh.a.ce[j] = 1.f / (1.f + expf(-cent[n * HW_ + j]));
    __syncthreads();
    #pragma unroll
    for (int it = 0; it < 7; ++it) {
      int j = it * 1024 + tid;
      if (j < SLICE) {
        float aa = cls[base + j];
        float s = 1.f / (1.f + expf(-aa));
        unsigned key = 0;
        // conservative band: f32 s <= 0.0499999 implies exact sigmoid < 0.05; borderline
        // entries get the exact f64 gate in phase C. (r6-proven scheme)
        if (s > 0.0499999f) {
          key = __float_as_uint(s * sh.a.ce[j % HW_]);   // >0 always
          int bin = (int)(key >> 16) - 0x3800;
          bin = bin < 0 ? 0 : (bin > NB - 1 ? NB - 1 : bin);
          atomicAdd(&sh.a.hist[bin], 1u);
        }
        sh.a.key[j] = key;
      }
    }
    __syncthreads();
    unsigned* gh = ghist + ((size_t)n * KB + sb) * NB;
    for (int j = tid; j < NB; j += 1024) gh[j] = sh.a.hist[j];
  } else if (b < N_ * KB + 140) {
    int g = tid >> 8, sub = tid & 255;
    int tt = (b - N_ * KB) * 4 + g;             // 0..559
    int n = tt / 280, r = tt % 280, rqt = r / 7, ct = r % 7;
    int tx = sub & 31, ty = sub >> 5;           // 32x8
    int rq0 = rqt * 32, c0 = ct * 32;
    for (int i = 0; i < 4; ++i) {
      int cc = c0 + ty + i * 8, rq = rq0 + tx;
      if (cc < M2_) {
        float v = bm[((size_t)n * M2_ + cc) * HW_ + rq];
        sh.m.tile[g][ty + i * 8][tx] = 1.f / (1.f + expf(-v));
      }
    }
    __syncthreads();
    for (int i = 0; i < 4; ++i) {
      int rq = rq0 + ty + i * 8, cc = c0 + tx;
      if (cc < M2_) msig[((size_t)n * HW_ + rq) * M2_ + cc] = sh.m.tile[g][tx][ty + i * 8];
    }
  } else if (b == N_ * KB + 140) {
    int t = tid;
    if (t < H_) {
      int r = t; float acc = 0.f; wr[0 * H_ + r] = 0.f;
      for (int x = 0; x < IMH; ++x) {
        float src = ((float)x + 0.5f) * ((float)H_ / (float)IMH) - 0.5f;
        src = fminf(fmaxf(src, 0.f), (float)(H_ - 1));
        int i0 = (int)floorf(src); int i1 = min(i0 + 1, H_ - 1);
        float lam = src - (float)i0;
        float w = ((r == i0) ? (1.f - lam) : 0.f) + ((r == i1) ? lam : 0.f);
        acc += w; wr[(x + 1) * H_ + r] = acc;
      }
    } else if (t < H_ + W_) {
      int q = t - H_; float acc = 0.f; wc[0 * W_ + q] = 0.f;
      for (int y = 0; y < IMW; ++y) {
        float src = ((float)y + 0.5f) * ((float)W_ / (float)IMW) - 0.5f;
        src = fminf(fmaxf(src, 0.f), (float)(W_ - 1));
        int i0 = (int)floorf(src); int i1 = min(i0 + 1, W_ - 1);
        float lam = src - (float)i0;
        float w = ((q == i0) ? (1.f - lam) : 0.f) + ((q == i1) ? lam : 0.f);
        acc += w; wc[(y + 1) * W_ + q] = acc;
      }
    }
  }
  gg.sync();  // ---- 1 ----

  // ================= Phase B: redundant D + per-slice compact (from LDS keys) =================
  if (b < N_ * KB) {
    int n = b >> 4, sb = b & 15;
    const unsigned* gh = ghist + (size_t)n * KB * NB;
    unsigned a = 0, bv = 0;
    #pragma unroll
    for (int q = 0; q < KB; ++q) { a += gh[q * NB + 2 * tid]; bv += gh[q * NB + 2 * tid + 1]; }
    if (tid == 0) { sh.a.sD = 0; sh.a.lcnt = 0; }
    unsigned s2 = a + bv, suf = s2;
    for (int off = 1; off < 64; off <<= 1) {
      unsigned v = __shfl_down(suf, off);
      if (lane + off < 64) suf += v;
    }
    if (lane == 0) sh.a.wtot[wid] = suf;
    __syncthreads();
    if (tid == 0) { unsigned acc = 0; for (int w = 15; w >= 0; --w) { sh.a.wabove[w] = acc; acc += sh.a.wtot[w]; } }
    __syncthreads();
    unsigned above = (suf - s2) + sh.a.wabove[wid];
    if (above < 1000u && above + bv >= 1000u) sh.a.sD = (unsigned)(2 * tid + 1);
    if (above + bv < 1000u && above + bv + a >= 1000u) sh.a.sD = (unsigned)(2 * tid);
    __syncthreads();
    unsigned D = sh.a.sD;
    unsigned Dg = (D > 0) ? D - 1 : 0;          // guard bin covers f32-vs-f64 straddle
    {
      unsigned acc = 0;
      for (int bin = (int)Dg + lane; bin < NB; bin += 64) acc += gh[wid * NB + bin];
      for (int off = 32; off; off >>= 1) acc += __shfl_down(acc, off);
      if (lane == 0) sh.a.sliceCnt[wid] = acc;
    }
    __syncthreads();
    if (tid == 0) {
      unsigned acc = 0;
      for (int q = 0; q < KB; ++q) { sh.a.sliceOff[q] = acc; acc += sh.a.sliceCnt[q]; }
      sh.a.sliceOff[KB] = acc;
      if (sb == 0) cntG[n] = acc;
    }
    __syncthreads();
    unsigned myStart = sh.a.sliceOff[sb];
    #pragma unroll
    for (int it = 0; it < 7; ++it) {
      int j = it * 1024 + tid;
      bool win = false;
      if (j < SLICE) {
        unsigned key = sh.a.key[j];
        if (key) {
          int bin = (int)(key >> 16) - 0x3800;
          bin = bin < 0 ? 0 : (bin > NB - 1 ? NB - 1 : bin);
          win = (unsigned)bin >= Dg;
        }
      }
      unsigned long long mb = __ballot(win);
      if (mb) {
        int lead = __builtin_ctzll(mb);
        unsigned offw = 0;
        if (lane == lead) offw = atomicAdd(&sh.a.lcnt, (unsigned)__popcll(mb));
        offw = (unsigned)__shfl((int)offw, lead);
        if (win) {
          unsigned pos = myStart + offw + (unsigned)__popcll(mb & ((1ull << lane) - 1ull));
          if (pos < (unsigned)BCAP)
            bufI[(size_t)n * BCAP + pos] = (unsigned)((j % HW_) * C_ + (sb * 5 + j / HW_));
        }
      }
    }
  }
  gg.sync();  // ---- 2 ----

  // ================= Phase C: gather -> exact f64 keys -> sort -> decode | zero keepg =================
  if (b < N_) {
    int n = b;
    unsigned cnt = cntG[n]; if (cnt > (unsigned)BCAP) cnt = BCAP;
    for (unsigned pos = tid; pos < cnt; pos += 1024) {
      unsigned idx = bufI[(size_t)n * BCAP + pos];   // logical [HW,C] flat index
      int hw = (int)(idx / C_), c = (int)(idx % C_);
      double aa = (double)cls[(size_t)n * HWC_ + (size_t)c * HW_ + hw];
      double ss = 1.0 / (1.0 + exp(-aa));
      double ced = 1.0 / (1.0 + exp(-(double)cent[n * HW_ + hw]));
      double v = (ss > 0.05) ? ss * ced : -1e9;
      sh.c.K[pos] = mapd(v);
      sh.c.I[pos] = idx;
    }
    int P = 1024; while (P < (int)cnt) P <<= 1;
    for (int j = (int)cnt + tid; j < P; j += 1024) { sh.c.K[j] = 0ull; sh.c.I[j] = 0xFFFFFFFFu; }
    __syncthreads();
    int E = P >> 10;
    for (int sz = 2; sz <= P; sz <<= 1) {
      for (int st = sz >> 1; st >= 64; st >>= 1) {
        for (int p = tid; p < (P >> 1); p += 1024) {
          int i = ((p & ~(st - 1)) << 1) | (p & (st - 1));
          int j = i | st;
          bool up = ((i & sz) == 0);
          unsigned long long k1 = sh.c.K[i], k2 = sh.c.K[j];
          unsigned i1 = sh.c.I[i], i2 = sh.c.I[j];
          bool bef = (k1 > k2) || (k1 == k2 && i1 < i2);
          if (bef != up) { sh.c.K[i] = k2; sh.c.K[j] = k1; sh.c.I[i] = i2; sh.c.I[j] = i1; }
        }
        __syncthreads();
      }
      {
        int st0 = ((sz >> 1) < 32) ? (sz >> 1) : 32;
        for (int e = 0; e < E; ++e) {
          int elem = tid + (e << 10);
          unsigned long long k = sh.c.K[elem];
          unsigned ii = sh.c.I[elem];
          bool dir = ((elem & sz) == 0);
          for (int st = st0; st >= 1; st >>= 1) {
            unsigned long long ko = __shfl_xor(k, st);
            unsigned io = __shfl_xor(ii, st);
            bool low = ((elem & st) == 0);
            bool first = (k > ko) || (k == ko && ii < io);
            bool take_mine = first ^ (!low) ^ (!dir);
            if (!take_mine) { k = ko; ii = io; }
          }
          sh.c.K[elem] = k; sh.c.I[elem] = ii;
        }
        __syncthreads();
      }
    }
    // decode top-1000 (f64, exact vs np ref)
    if (tid < KTOP) {
      unsigned long long key = sh.c.K[tid];
      unsigned idx = sh.c.I[tid];
      double v = unmapd(key);
      int valid = (v > -5e8) && (idx < (unsigned)HWC_);
      if (idx >= (unsigned)HWC_) idx = 0;
      int hw = (int)(idx / C_), c = (int)(idx % C_);
      double lx = (double)loc[hw * 2 + 0], ly = (double)loc[hw * 2 + 1];
      const float* rg4 = breg + (size_t)n * 4 * HW_;
      double r0 = (double)rg4[0 * HW_ + hw], r1 = (double)rg4[1 * HW_ + hw];
      double r2 = (double)rg4[2 * HW_ + hw], r3 = (double)rg4[3 * HW_ + hw];
      double b0 = lx - r0, b1 = ly - r1, b2 = lx + r2, b3 = ly + r3;
      double sc = valid ? sqrt(v) : 0.0;
      int bi0 = (int)b0, bi1 = (int)b1, bi2 = (int)b2, bi3 = (int)b3;
      int x1 = max(bi0, 0), x2 = min(bi2, IMH - 1), y1 = max(bi1, 0), y2 = min(bi3, IMW - 1);
      int rok = (x1 < x2) && (y1 < x2) && (y1 < y2);   // ref bug replicated
      int x1c = min(max(x1, 0), IMH), x2c = min(max(x2, 0), IMH);
      int y1c = min(max(y1, 0), IMW), y2c = min(max(y2, 0), IMW);
      int area = max((x2c - x1c) * (y2c - y1c), 1);
      double c0 = fmin(fmax(b0, 0.0), (double)(IMW - 1));
      double c1 = fmin(fmax(b1, 0.0), (double)(IMH - 1));
      double c2 = fmin(fmax(b2, 0.0), (double)(IMW - 1));
      double c3 = fmin(fmax(b3, 0.0), (double)(IMH - 1));
      size_t base = (size_t)n * 1024 + tid;
      bxd[base * 4 + 0] = c0; bxd[base * 4 + 1] = c1; bxd[base * 4 + 2] = c2; bxd[base * 4 + 3] = c3;
      scd[base] = sc; lab[base] = c + 1; vld[base] = valid;
      int* r8 = rg + base * 8;
      r8[0] = x1c; r8[1] = x2c; r8[2] = y1c; r8[3] = y2c; r8[4] = area; r8[5] = rok;
    }
  } else if (b < N_ + 2) {
    keepg[(b - N_) * 1024 + tid] = 0;
  }
  gg.sync();  // ---- 3 ----

  // ================= Phase D: per-(image,class) greedy NMS, single wave, register masks =================
  if (b < N_ * C_) {
    int cls_ = (b % C_) + 1, n = b / C_;
    if (tid < 64) {
      int m = 0;
      for (int ch = 0; ch < 16; ++ch) {
        int e = ch * 64 + lane;
        bool pred = (e < KTOP) && vld[n * 1024 + e] && (lab[n * 1024 + e] == cls_);
        unsigned long long bb = __ballot(pred);
        if (pred) {
          int pos = m + (int)__popcll(bb & ((1ull << lane) - 1ull));
          if (pos < 128) {
            const double* p = bxd + ((size_t)n * 1024 + e) * 4;
            double b0 = p[0], b1 = p[1], b2 = p[2], b3 = p[3];
            sh.d.bx[pos][0] = b0; sh.d.bx[pos][1] = b1; sh.d.bx[pos][2] = b2; sh.d.bx[pos][3] = b3;
            sh.d.bx[pos][4] = (b2 - b0 + 1.0) * (b3 - b1 + 1.0);
            sh.d.ml[pos] = (unsigned short)e;
          }
        }
        m += (int)__popcll(bb);
      }
      if (m > 128) m = 128;
      __builtin_amdgcn_wave_barrier();   // single-wave: LDS ops are program-ordered within the wave
      unsigned long long k0 = (m >= 64) ? ~0ull : ((1ull << m) - 1ull);
      unsigned long long k1m = (m > 64) ? ((m >= 128) ? ~0ull : ((1ull << (m - 64)) - 1ull)) : 0ull;
      for (int i = 0; i < m; ++i) {
        bool alive = (i < 64) ? ((k0 >> i) & 1ull) : ((k1m >> (i - 64)) & 1ull);
        if (!alive) continue;            // uniform (mask identical across lanes)
        double x1 = sh.d.bx[i][0], y1 = sh.d.bx[i][1], x2 = sh.d.bx[i][2], y2 = sh.d.bx[i][3], ai = sh.d.bx[i][4];
        {
          int j = lane;
          bool ok = (j < m) && (j > i);
          int jj = ok ? j : 0;
          double u1 = sh.d.bx[jj][0], v1 = sh.d.bx[jj][1], u2 = sh.d.bx[jj][2], v2 = sh.d.bx[jj][3], aj = sh.d.bx[jj][4];
          double ltx = fmax(x1, u1), lty = fmax(y1, v1), rbx = fmin(x2, u2), rby = fmin(y2, v2);
          double iw = fmax(rbx - ltx + 1.0, 0.0), ih = fmax(rby - lty + 1.0, 0.0);
          double inter = iw * ih, uni = ai + aj - inter;
          bool sup = ok && (inter / fmax(uni, 1e-6) > 0.6);
          k0 &= ~__ballot(sup);
        }
        if (m > 64) {
          int j = 64 + lane;
          bool ok = (j < m) && (j > i);
          int jj = ok ? j : 0;
          double u1 = sh.d.bx[jj][0], v1 = sh.d.bx[jj][1], u2 = sh.d.bx[jj][2], v2 = sh.d.bx[jj][3], aj = sh.d.bx[jj][4];
          double ltx = fmax(x1, u1), lty = fmax(y1, v1), rbx = fmin(x2, u2), rby = fmin(y2, v2);
          double iw = fmax(rbx - ltx + 1.0, 0.0), ih = fmax(rby - lty + 1.0, 0.0);
          double inter = iw * ih, uni = ai + aj - inter;
          bool sup = ok && (inter / fmax(uni, 1e-6) > 0.6);
          k1m &= ~__ballot(sup);
        }
      }
      for (int j = lane; j < m; j += 64) {
        bool kb = (j < 64) ? ((k0 >> j) & 1ull) : ((k1m >> (j - 64)) & 1ull);
        keepg[n * 1024 + sh.d.ml[j]] = kb ? 1u : 0u;
      }
    }
  }
  gg.sync();  // ---- 4 ----

  // ================= Phase E: stable partition + outputs + mask prob (all 200 blocks) =================
  {
    int t = b % 100, n = b / 100;
    int kp = (tid < KTOP) ? (int)keepg[n * 1024 + tid] : 0;
    unsigned long long bal = __ballot(kp != 0);
    int posw = (int)__popcll(bal & ((1ull << lane) - 1ull));
    if (lane == 0) sh.e.wcnt[wid] = (unsigned)__popcll(bal);
    __syncthreads();
    if (tid == 0) { unsigned acc = 0; for (int i = 0; i < 16; ++i) { sh.e.woff[i] = acc; acc += sh.e.wcnt[i]; } sh.e.Stot = acc; }
    __syncthreads();
    int posK = (int)sh.e.woff[wid] + posw;
    int S = (int)sh.e.Stot;
    if (tid < KTOP) {
      if (kp) { if (posK < 100) { sh.e.lsel[posK] = tid; sh.e.lvf[posK] = 1; } }
      else { int slot = S + (tid - posK); if (slot < 100) { sh.e.lsel[slot] = tid; sh.e.lvf[slot] = 0; } }
    }
    __syncthreads();
    int k = sh.e.lsel[t], vf = sh.e.lvf[t];
    if (tid == 0) {
      const double* bb = bxd + ((size_t)n * 1024 + k) * 4;
      out[(n * 100 + t) * 4 + 0] = (float)bb[0];
      out[(n * 100 + t) * 4 + 1] = (float)bb[1];
      out[(n * 100 + t) * 4 + 2] = (float)bb[2];
      out[(n * 100 + t) * 4 + 3] = (float)bb[3];
      out[O_SC + n * 100 + t] = vf ? (float)scd[n * 1024 + k] : 0.f;
      out[O_LB + n * 100 + t] = (float)lab[n * 1024 + k];
      out[O_VF + n * 100 + t] = (float)vf;
    }
    const int* r8 = rg + ((size_t)n * 1024 + k) * 8;
    int x1c = r8[0], x2c = r8[1], y1c = r8[2], y2c = r8[3], area = r8[4], rok = r8[5];
    if (tid < H_) sh.e.A[tid] = wr[x2c * H_ + tid] - wr[x1c * H_ + tid];
    else if (tid < H_ + W_) { int q = tid - H_; sh.e.Bw[q] = wc[y2c * W_ + q] - wc[y1c * W_ + q]; }
    __syncthreads();
    if (tid < M2_) {
      float acc = 0.f;
      if (rok && vf) {
        int rlo = i0of(x1c, H_ - 1);
        int rhi = min(i0of(x2c - 1, H_ - 1) + 1, H_ - 1);
        int qlo = i0of(y1c, W_ - 1);
        int qhi = min(i0of(y2c - 1, W_ - 1) + 1, W_ - 1);
        for (int r = rlo; r <= rhi; ++r) {
          float ar = sh.e.A[r];
          const float* mrow = msig + ((size_t)((n * H_ + r) * W_ + qlo)) * M2_ + tid;
          float rs = 0.f;
          #pragma unroll 4
          for (int q = qlo; q <= qhi; ++q) { rs += sh.e.Bw[q] * mrow[0]; mrow += M2_; }
          acc += ar * rs;
        }
        acc /= (float)area;
      }
      out[O_PB + (size_t)(n * 100 + t) * M2_ + tid] = acc;
    }
  }
}

extern "C" void kernel_launch(void* const* d_in, const int* in_sizes, int n_in,
                              void* d_out, int out_size, void* d_ws, size_t ws_size,
                              hipStream_t stream) {
  (void)in_sizes; (void)n_in; (void)out_size; (void)ws_size;
  const float* locations = (const float*)d_in[0];
  const float* box_cls   = (const float*)d_in[1];
  const float* box_reg   = (const float*)d_in[2];
  const float* cent      = (const float*)d_in[3];
  const float* box_mask  = (const float*)d_in[4];
  float* out = (float*)d_out;

  char* ws = (char*)d_ws;
  size_t off = 0;
  auto alloc = [&](size_t bytes) -> void* {
    void* p = ws + off;
    off = (off + bytes + 255) & ~(size_t)255;
    return p;
  };
  unsigned* ghist = (unsigned*)alloc((size_t)N_ * KB * NB * 4);
  unsigned* bufI  = (unsigned*)alloc((size_t)N_ * BCAP * 4);
  unsigned* cntG  = (unsigned*)alloc(16 * 4);
  double* bxd     = (double*)alloc((size_t)N_ * 1024 * 4 * 8);
  double* scd     = (double*)alloc((size_t)N_ * 1024 * 8);
  int* lab        = (int*)alloc((size_t)N_ * 1024 * 4);
  int* vld        = (int*)alloc((size_t)N_ * 1024 * 4);
  int* rg         = (int*)alloc((size_t)N_ * 1024 * 8 * 4);
  unsigned* keepg = (unsigned*)alloc((size_t)N_ * 1024 * 4);
  float* msig     = (float*)alloc((size_t)N_ * HW_ * M2_ * 4);
  float* wr       = (float*)alloc((size_t)(IMH + 1) * H_ * 4);
  float* wc       = (float*)alloc((size_t)(IMW + 1) * W_ * 4);

  void* args[] = { (void*)&box_cls, (void*)&cent, (void*)&box_mask, (void*)&locations, (void*)&box_reg,
                   (void*)&ghist, (void*)&bufI, (void*)&cntG, (void*)&bxd, (void*)&scd,
                   (void*)&lab, (void*)&vld, (void*)&rg, (void*)&keepg, (void*)&msig,
                   (void*)&wr, (void*)&wc, (void*)&out };
  hipLaunchCooperativeKernel((void*)mega, dim3(GBLK), dim3(1024), args, 0, stream);
}

// Round 8
// 138.012 us; speedup vs baseline: 1.2988x; 1.2988x over previous
//
#include <hip/hip_runtime.h>

#define DEVI __device__ __forceinline__

constexpr int N_ = 2, C_ = 80, H_ = 32, W_ = 40, HW_ = H_ * W_, HWC_ = HW_ * C_;
constexpr int KTOP = 1000, M2_ = 196;
constexpr int IMH = 256, IMW = 320;
constexpr int NB = 2048;          // f32-derived bins
constexpr int KB = 16;            // hist slices per image
constexpr int SLICE = HWC_ / KB;  // 6400
constexpr int BCAP = 4096;        // compacted-candidate cap (expected G ~ 1100)

// output layout (floats): bx[2][100][4] | sc[2][100] | lb[2][100] | prob[2][100][196] | vf[2][100]
constexpr int O_SC = 800, O_LB = 1000, O_PB = 1200, O_VF = 40400;

DEVI unsigned long long mapd(double v) {
  unsigned long long u = (unsigned long long)__double_as_longlong(v);
  return (u & 0x8000000000000000ull) ? ~u : (u | 0x8000000000000000ull);
}
DEVI double unmapd(unsigned long long k) {
  unsigned long long u = (k & 0x8000000000000000ull) ? (k ^ 0x8000000000000000ull) : ~k;
  return __longlong_as_double((long long)u);
}
DEVI int i0of(int x, int cap) {  // exact first contributing mask row/col (matches table arithmetic)
  float src = ((float)x + 0.5f) * 0.125f - 0.5f;
  src = fminf(fmaxf(src, 0.f), (float)cap);
  return (int)floorf(src);
}

// ---- K1: per-slice f32 hist | mask transpose/sigmoid | weight tables ----
__global__ __launch_bounds__(1024) void k_pre(const float* cls, const float* cent, const float* bm,
                                              unsigned* ghist, float* msig, float* wr, float* wc) {
  int b = blockIdx.x, tid = threadIdx.x;
  if (b < N_ * KB) {
    __shared__ unsigned hist[NB];
    __shared__ float ce[HW_];
    int n = b >> 4, sb = b & 15;
    size_t base = (size_t)n * HWC_ + (size_t)sb * SLICE;
    for (int j = tid; j < NB; j += 1024) hist[j] = 0;
    for (int j = tid; j < HW_; j += 1024) ce[j] = 1.f / (1.f + expf(-cent[n * HW_ + j]));
    __syncthreads();
    #pragma unroll
    for (int it = 0; it < 7; ++it) {
      int j = it * 1024 + tid;
      if (j < SLICE) {
        float aa = cls[base + j];
        float s = 1.f / (1.f + expf(-aa));
        // conservative band: f32 s <= 0.0499999 implies exact sigmoid < 0.05 (exclude safely);
        // borderline entries get the exact f64 gate in K2. (r6/r7-proven scheme)
        if (s > 0.0499999f) {
          unsigned key = __float_as_uint(s * ce[j % HW_]);   // base is a multiple of HW_
          int bin = (int)(key >> 16) - 0x3800;
          bin = bin < 0 ? 0 : (bin > NB - 1 ? NB - 1 : bin);
          atomicAdd(&hist[bin], 1u);
        }
      }
    }
    __syncthreads();
    unsigned* gh = ghist + ((size_t)n * KB + sb) * NB;
    for (int j = tid; j < NB; j += 1024) gh[j] = hist[j];
  } else if (b < N_ * KB + 140) {
    __shared__ float tile[4][32][33];
    int g = tid >> 8, sub = tid & 255;
    int tt = (b - N_ * KB) * 4 + g;             // 0..559
    int n = tt / 280, r = tt % 280, rqt = r / 7, ct = r % 7;
    int tx = sub & 31, ty = sub >> 5;           // 32x8
    int rq0 = rqt * 32, c0 = ct * 32;
    for (int i = 0; i < 4; ++i) {
      int cc = c0 + ty + i * 8, rq = rq0 + tx;
      if (cc < M2_) {
        float v = bm[((size_t)n * M2_ + cc) * HW_ + rq];
        tile[g][ty + i * 8][tx] = 1.f / (1.f + expf(-v));
      }
    }
    __syncthreads();
    for (int i = 0; i < 4; ++i) {
      int rq = rq0 + ty + i * 8, cc = c0 + tx;
      if (cc < M2_) msig[((size_t)n * HW_ + rq) * M2_ + cc] = tile[g][tx][ty + i * 8];
    }
  } else {
    int t = tid;
    if (t < H_) {
      int r = t; float acc = 0.f; wr[0 * H_ + r] = 0.f;
      for (int x = 0; x < IMH; ++x) {
        float src = ((float)x + 0.5f) * ((float)H_ / (float)IMH) - 0.5f;
        src = fminf(fmaxf(src, 0.f), (float)(H_ - 1));
        int i0 = (int)floorf(src); int i1 = min(i0 + 1, H_ - 1);
        float lam = src - (float)i0;
        float w = ((r == i0) ? (1.f - lam) : 0.f) + ((r == i1) ? lam : 0.f);
        acc += w; wr[(x + 1) * H_ + r] = acc;
      }
    } else if (t < H_ + W_) {
      int q = t - H_; float acc = 0.f; wc[0 * W_ + q] = 0.f;
      for (int y = 0; y < IMW; ++y) {
        float src = ((float)y + 0.5f) * ((float)W_ / (float)IMW) - 0.5f;
        src = fminf(fmaxf(src, 0.f), (float)(W_ - 1));
        int i0 = (int)floorf(src); int i1 = min(i0 + 1, W_ - 1);
        float lam = src - (float)i0;
        float w = ((q == i0) ? (1.f - lam) : 0.f) + ((q == i1) ? lam : 0.f);
        acc += w; wc[(y + 1) * W_ + q] = acc;
      }
    }
  }
}

// ---- K2: per-image: hist-reduce -> D,Dg -> sweep-compact (f32) -> exact f64 keys -> sort -> decode ----
struct SortSh { unsigned long long K[BCAP]; unsigned I[BCAP]; };

__global__ __launch_bounds__(1024) void k_seldec(const unsigned* ghist, const float* cls,
                                                 const float* cent, const float* loc, const float* breg,
                                                 double* bxd, double* scd, int* lab, int* vld, int* rg,
                                                 unsigned* keepg) {
  __shared__ SortSh sh;
  __shared__ float ce[HW_];
  __shared__ unsigned wtot[16], wabove[16];
  __shared__ unsigned sD, sCnt;
  int n = blockIdx.x, tid = threadIdx.x, lane = tid & 63, wid = tid >> 6;
  keepg[n * 1024 + tid] = 0;
  for (int j = tid; j < HW_; j += 1024) ce[j] = 1.f / (1.f + expf(-cent[n * HW_ + j]));
  // -- reduce 16 part-hists; thread owns bins 2tid, 2tid+1; suffix scan (r5-proven) --
  const unsigned* gh = ghist + (size_t)n * KB * NB;
  unsigned a = 0, bv = 0;
  #pragma unroll
  for (int q = 0; q < KB; ++q) { a += gh[q * NB + 2 * tid]; bv += gh[q * NB + 2 * tid + 1]; }
  if (tid == 0) { sD = 0; sCnt = 0; }
  unsigned s2 = a + bv, suf = s2;
  for (int off = 1; off < 64; off <<= 1) {
    unsigned v = __shfl_down(suf, off);
    if (lane + off < 64) suf += v;
  }
  if (lane == 0) wtot[wid] = suf;
  __syncthreads();
  if (tid == 0) { unsigned acc = 0; for (int w = 15; w >= 0; --w) { wabove[w] = acc; acc += wtot[w]; } }
  __syncthreads();
  unsigned above = (suf - s2) + wabove[wid];
  if (above < 1000u && above + bv >= 1000u) sD = (unsigned)(2 * tid + 1);
  if (above + bv < 1000u && above + bv + a >= 1000u) sD = (unsigned)(2 * tid);
  __syncthreads();
  unsigned D = sD;
  int Dg = (D > 0) ? (int)D - 1 : 0;            // guard bin covers f32-vs-f64 straddle (r6-proven)

  // -- sweep-compact: recompute f32 keys, winners' indices straight into LDS --
  const float* cb = cls + (size_t)n * HWC_;
  for (int it = 0; it < HWC_ / 1024; ++it) {
    int j = it * 1024 + tid;
    float aa = cb[j];
    float s = 1.f / (1.f + expf(-aa));
    bool win = false;
    if (s > 0.0499999f) {
      unsigned key = __float_as_uint(s * ce[j % HW_]);
      int bin = (int)(key >> 16) - 0x3800;
      bin = bin < 0 ? 0 : (bin > NB - 1 ? NB - 1 : bin);
      win = (bin >= Dg);
    }
    unsigned long long mb = __ballot(win);
    if (mb) {
      int lead = __builtin_ctzll(mb);
      unsigned offw = 0;
      if (lane == lead) offw = atomicAdd(&sCnt, (unsigned)__popcll(mb));
      offw = (unsigned)__shfl((int)offw, lead);
      if (win) {
        unsigned pos = offw + (unsigned)__popcll(mb & ((1ull << lane) - 1ull));
        if (pos < (unsigned)BCAP)
          sh.I[pos] = (unsigned)((j % HW_) * C_ + j / HW_);  // logical [HW,C] flat index
      }
    }
  }
  __syncthreads();
  int G = (int)sCnt; if (G > BCAP) G = BCAP;
  // -- exact f64 keys for winners only (r7-phase-C-proven numerics, matches np ref bitwise) --
  for (int pos = tid; pos < G; pos += 1024) {
    unsigned idx = sh.I[pos];
    int hw = (int)(idx / C_), c = (int)(idx % C_);
    double aa = (double)cls[(size_t)n * HWC_ + (size_t)c * HW_ + hw];
    double ss = 1.0 / (1.0 + exp(-aa));
    double ced = 1.0 / (1.0 + exp(-(double)cent[n * HW_ + hw]));
    double v = (ss > 0.05) ? ss * ced : -1e9;
    sh.K[pos] = mapd(v);
  }
  int P = 1024; while (P < G) P <<= 1;
  for (int j = G + tid; j < P; j += 1024) { sh.K[j] = 0ull; sh.I[j] = 0xFFFFFFFFu; }
  __syncthreads();
  // -- bitonic sort by (key desc, idx asc): LDS rounds for stride>=64, shfl for <=32 (r5-proven) --
  int E = P >> 10;
  for (int sz = 2; sz <= P; sz <<= 1) {
    for (int st = sz >> 1; st >= 64; st >>= 1) {
      for (int p = tid; p < (P >> 1); p += 1024) {
        int i = ((p & ~(st - 1)) << 1) | (p & (st - 1));
        int j = i | st;
        bool up = ((i & sz) == 0);
        unsigned long long k1 = sh.K[i], k2 = sh.K[j];
        unsigned i1 = sh.I[i], i2 = sh.I[j];
        bool bef = (k1 > k2) || (k1 == k2 && i1 < i2);
        if (bef != up) { sh.K[i] = k2; sh.K[j] = k1; sh.I[i] = i2; sh.I[j] = i1; }
      }
      __syncthreads();
    }
    {
      int st0 = ((sz >> 1) < 32) ? (sz >> 1) : 32;
      for (int e = 0; e < E; ++e) {
        int elem = tid + (e << 10);
        unsigned long long k = sh.K[elem];
        unsigned ii = sh.I[elem];
        bool dir = ((elem & sz) == 0);
        for (int st = st0; st >= 1; st >>= 1) {
          unsigned long long ko = __shfl_xor(k, st);
          unsigned io = __shfl_xor(ii, st);
          bool low = ((elem & st) == 0);
          bool first = (k > ko) || (k == ko && ii < io);
          bool take_mine = first ^ (!low) ^ (!dir);
          if (!take_mine) { k = ko; ii = io; }
        }
        sh.K[elem] = k; sh.I[elem] = ii;
      }
      __syncthreads();
    }
  }
  // -- decode top-1000 (f64, exact vs np ref) -> per-candidate globals (verbatim r5) --
  if (tid < KTOP) {
    unsigned long long key = sh.K[tid];
    unsigned idx = sh.I[tid];
    double v = unmapd(key);
    int valid = (v > -5e8) && (idx < (unsigned)HWC_);
    if (idx >= (unsigned)HWC_) idx = 0;
    int hw = (int)(idx / C_), c = (int)(idx % C_);
    double lx = (double)loc[hw * 2 + 0], ly = (double)loc[hw * 2 + 1];
    const float* rg4 = breg + (size_t)n * 4 * HW_;
    double r0 = (double)rg4[0 * HW_ + hw], r1 = (double)rg4[1 * HW_ + hw];
    double r2 = (double)rg4[2 * HW_ + hw], r3 = (double)rg4[3 * HW_ + hw];
    double b0 = lx - r0, b1 = ly - r1, b2 = lx + r2, b3 = ly + r3;
    double sc = valid ? sqrt(v) : 0.0;
    int bi0 = (int)b0, bi1 = (int)b1, bi2 = (int)b2, bi3 = (int)b3;
    int x1 = max(bi0, 0), x2 = min(bi2, IMH - 1), y1 = max(bi1, 0), y2 = min(bi3, IMW - 1);
    int rok = (x1 < x2) && (y1 < x2) && (y1 < y2);   // ref bug replicated
    int x1c = min(max(x1, 0), IMH), x2c = min(max(x2, 0), IMH);
    int y1c = min(max(y1, 0), IMW), y2c = min(max(y2, 0), IMW);
    int area = max((x2c - x1c) * (y2c - y1c), 1);
    double c0 = fmin(fmax(b0, 0.0), (double)(IMW - 1));
    double c1 = fmin(fmax(b1, 0.0), (double)(IMH - 1));
    double c2 = fmin(fmax(b2, 0.0), (double)(IMW - 1));
    double c3 = fmin(fmax(b3, 0.0), (double)(IMH - 1));
    size_t base = (size_t)n * 1024 + tid;
    bxd[base * 4 + 0] = c0; bxd[base * 4 + 1] = c1; bxd[base * 4 + 2] = c2; bxd[base * 4 + 3] = c3;
    scd[base] = sc; lab[base] = c + 1; vld[base] = valid;
    int* r8 = rg + base * 8;
    r8[0] = x1c; r8[1] = x2c; r8[2] = y1c; r8[3] = y2c; r8[4] = area; r8[5] = rok;
  }
}

// ---- K3: per-(image,class) greedy NMS (verbatim r5) ----
__global__ void k_nms(const double* bxd, const int* lab, const int* vld, unsigned* keepg) {
  int cls = blockIdx.x + 1, n = blockIdx.y, tid = threadIdx.x; // 64 threads = 1 wave
  __shared__ int mk[KTOP];
  __shared__ double mb0[KTOP], mb1[KTOP], mb2[KTOP], mb3[KTOP], ma[KTOP];
  __shared__ unsigned char kept[KTOP];
  int m = 0;
  for (int base = 0; base < KTOP; base += 64) {
    int t = base + tid;
    bool pred = (t < KTOP) && (lab[n * 1024 + t] == cls) && (vld[n * 1024 + t] != 0);
    unsigned long long bb = __ballot(pred);
    if (pred) {
      int pos = m + (int)__popcll(bb & ((1ull << tid) - 1ull));
      mk[pos] = t;
      const double* p = bxd + ((size_t)n * 1024 + t) * 4;
      double b0 = p[0], b1 = p[1], b2 = p[2], b3 = p[3];
      mb0[pos] = b0; mb1[pos] = b1; mb2[pos] = b2; mb3[pos] = b3;
      ma[pos] = (b2 - b0 + 1.0) * (b3 - b1 + 1.0);
      kept[pos] = 1;
    }
    m += (int)__popcll(bb);
  }
  __syncthreads();
  for (int i = 0; i < m; ++i) {
    if (kept[i]) {
      double x1 = mb0[i], y1 = mb1[i], x2 = mb2[i], y2 = mb3[i], ai = ma[i];
      for (int j = i + 1 + tid; j < m; j += 64) {
        double ltx = fmax(x1, mb0[j]), lty = fmax(y1, mb1[j]);
        double rbx = fmin(x2, mb2[j]), rby = fmin(y2, mb3[j]);
        double iw = fmax(rbx - ltx + 1.0, 0.0), ih = fmax(rby - lty + 1.0, 0.0);
        double inter = iw * ih;
        double uni = ai + ma[j] - inter;
        if (inter / fmax(uni, 1e-6) > 0.6) kept[j] = 0;
      }
    }
    __syncthreads();
  }
  for (int i = tid; i < m; i += 64) keepg[n * 1024 + mk[i]] = (unsigned)kept[i];
}

// ---- K4: fused stable partition + outputs + mask prob (verbatim r5) ----
__global__ __launch_bounds__(256) void k_finish(const unsigned* keepg, const double* bxd,
                                                const double* scd, const int* lab, const int* rg,
                                                const float* msig, const float* wr, const float* wc,
                                                float* out) {
  int t = blockIdx.x, n = blockIdx.y, tid = threadIdx.x, lane = tid & 63, wid = tid >> 6;
  __shared__ int lsel[100], lvf[100];
  __shared__ unsigned woff[4]; __shared__ unsigned sS;
  __shared__ float A[H_], B[W_];

  int i0 = tid * 4;
  unsigned ff[4]; int lc = 0;
  for (int j = 0; j < 4; ++j) {
    int i = i0 + j;
    ff[j] = (i < KTOP) ? keepg[n * 1024 + i] : 0u;
    lc += (int)ff[j];
  }
  unsigned pre = (unsigned)lc;
  for (int off = 1; off < 64; off <<= 1) {
    unsigned v = __shfl_up(pre, off);
    if (lane >= off) pre += v;
  }
  if (lane == 63) woff[wid] = pre;
  __syncthreads();
  if (tid == 0) { unsigned acc = 0; for (int w = 0; w < 4; ++w) { unsigned tmp = woff[w]; woff[w] = acc; acc += tmp; } sS = acc; }
  __syncthreads();
  int kpre = (int)(woff[wid] + pre - (unsigned)lc);
  int S = (int)sS;
  for (int j = 0; j < 4; ++j) {
    int i = i0 + j;
    if (i < KTOP) {
      if (ff[j]) { if (kpre < 100) { lsel[kpre] = i; lvf[kpre] = 1; } kpre++; }
      else { int slot = S + (i - kpre); if (slot < 100) { lsel[slot] = i; lvf[slot] = 0; } }
    }
  }
  __syncthreads();

  int k = lsel[t], vf = lvf[t];
  if (tid == 0) {
    const double* bb = bxd + ((size_t)n * 1024 + k) * 4;
    out[(n * 100 + t) * 4 + 0] = (float)bb[0];
    out[(n * 100 + t) * 4 + 1] = (float)bb[1];
    out[(n * 100 + t) * 4 + 2] = (float)bb[2];
    out[(n * 100 + t) * 4 + 3] = (float)bb[3];
    out[O_SC + n * 100 + t] = vf ? (float)scd[n * 1024 + k] : 0.f;
    out[O_LB + n * 100 + t] = (float)lab[n * 1024 + k];
    out[O_VF + n * 100 + t] = (float)vf;
  }
  const int* r8 = rg + ((size_t)n * 1024 + k) * 8;
  int x1c = r8[0], x2c = r8[1], y1c = r8[2], y2c = r8[3], area = r8[4], rok = r8[5];
  if (tid < H_) A[tid] = wr[x2c * H_ + tid] - wr[x1c * H_ + tid];
  else if (tid < H_ + W_) { int q = tid - H_; B[q] = wc[y2c * W_ + q] - wc[y1c * W_ + q]; }
  __syncthreads();
  if (tid < M2_) {
    float acc = 0.f;
    if (rok && vf) {
      int rlo = i0of(x1c, H_ - 1);
      int rhi = min(i0of(x2c - 1, H_ - 1) + 1, H_ - 1);
      int qlo = i0of(y1c, W_ - 1);
      int qhi = min(i0of(y2c - 1, W_ - 1) + 1, W_ - 1);
      for (int r = rlo; r <= rhi; ++r) {
        float ar = A[r];
        const float* mrow = msig + ((size_t)((n * H_ + r) * W_ + qlo)) * M2_ + tid;
        float rs = 0.f;
        #pragma unroll 4
        for (int q = qlo; q <= qhi; ++q) { rs += B[q] * mrow[0]; mrow += M2_; }
        acc += ar * rs;
      }
      acc /= (float)area;
    }
    out[O_PB + (size_t)(n * 100 + t) * M2_ + tid] = acc;
  }
}

extern "C" void kernel_launch(void* const* d_in, const int* in_sizes, int n_in,
                              void* d_out, int out_size, void* d_ws, size_t ws_size,
                              hipStream_t stream) {
  (void)in_sizes; (void)n_in; (void)out_size; (void)ws_size;
  const float* locations = (const float*)d_in[0];
  const float* box_cls   = (const float*)d_in[1];
  const float* box_reg   = (const float*)d_in[2];
  const float* cent      = (const float*)d_in[3];
  const float* box_mask  = (const float*)d_in[4];
  float* out = (float*)d_out;

  char* ws = (char*)d_ws;
  size_t off = 0;
  auto alloc = [&](size_t bytes) -> void* {
    void* p = ws + off;
    off = (off + bytes + 255) & ~(size_t)255;
    return p;
  };
  unsigned* ghist = (unsigned*)alloc((size_t)N_ * KB * NB * 4);
  double* bxd     = (double*)alloc((size_t)N_ * 1024 * 4 * 8);
  double* scd     = (double*)alloc((size_t)N_ * 1024 * 8);
  int* lab        = (int*)alloc((size_t)N_ * 1024 * 4);
  int* vld        = (int*)alloc((size_t)N_ * 1024 * 4);
  int* rg         = (int*)alloc((size_t)N_ * 1024 * 8 * 4);
  unsigned* keepg = (unsigned*)alloc((size_t)N_ * 1024 * 4);
  float* msig     = (float*)alloc((size_t)N_ * HW_ * M2_ * 4);
  float* wr       = (float*)alloc((size_t)(IMH + 1) * H_ * 4);
  float* wc       = (float*)alloc((size_t)(IMW + 1) * W_ * 4);

  k_pre<<<N_ * KB + 140 + 1, 1024, 0, stream>>>(box_cls, cent, box_mask, ghist, msig, wr, wc);
  k_seldec<<<N_, 1024, 0, stream>>>(ghist, box_cls, cent, locations, box_reg,
                                    bxd, scd, lab, vld, rg, keepg);
  k_nms<<<dim3(C_, N_), 64, 0, stream>>>(bxd, lab, vld, keepg);
  k_finish<<<dim3(100, N_), 256, 0, stream>>>(keepg, bxd, scd, lab, rg, msig, wr, wc, out);
}

// Round 9
// 128.318 us; speedup vs baseline: 1.3969x; 1.0755x over previous
//
#include <hip/hip_runtime.h>

#define DEVI __device__ __forceinline__

constexpr int N_ = 2, C_ = 80, H_ = 32, W_ = 40, HW_ = H_ * W_, HWC_ = HW_ * C_;
constexpr int KTOP = 1000, M2_ = 196;
constexpr int IMH = 256, IMW = 320;
constexpr int NB = 2048;          // f32-derived bins
constexpr int KB = 16;            // hist slices per image
constexpr int SLICE = HWC_ / KB;  // 6400
constexpr int BCAP = 4096;        // compacted-candidate cap (expected G ~ 1100)

// output layout (floats): bx[2][100][4] | sc[2][100] | lb[2][100] | prob[2][100][196] | vf[2][100]
constexpr int O_SC = 800, O_LB = 1000, O_PB = 1200, O_VF = 40400;

DEVI unsigned long long mapd(double v) {
  unsigned long long u = (unsigned long long)__double_as_longlong(v);
  return (u & 0x8000000000000000ull) ? ~u : (u | 0x8000000000000000ull);
}
DEVI double unmapd(unsigned long long k) {
  unsigned long long u = (k & 0x8000000000000000ull) ? (k ^ 0x8000000000000000ull) : ~k;
  return __longlong_as_double((long long)u);
}
DEVI int i0of(int x, int cap) {  // exact first contributing mask row/col (matches table arithmetic)
  float src = ((float)x + 0.5f) * 0.125f - 0.5f;
  src = fminf(fmaxf(src, 0.f), (float)cap);
  return (int)floorf(src);
}

// ---- K1: per-slice f32 hist | mask transpose/sigmoid | weight tables (verbatim r8) ----
__global__ __launch_bounds__(1024) void k_pre(const float* cls, const float* cent, const float* bm,
                                              unsigned* ghist, float* msig, float* wr, float* wc) {
  int b = blockIdx.x, tid = threadIdx.x;
  if (b < N_ * KB) {
    __shared__ unsigned hist[NB];
    __shared__ float ce[HW_];
    int n = b >> 4, sb = b & 15;
    size_t base = (size_t)n * HWC_ + (size_t)sb * SLICE;
    for (int j = tid; j < NB; j += 1024) hist[j] = 0;
    for (int j = tid; j < HW_; j += 1024) ce[j] = 1.f / (1.f + expf(-cent[n * HW_ + j]));
    __syncthreads();
    #pragma unroll
    for (int it = 0; it < 7; ++it) {
      int j = it * 1024 + tid;
      if (j < SLICE) {
        float aa = cls[base + j];
        float s = 1.f / (1.f + expf(-aa));
        // conservative band: f32 s <= 0.0499999 implies exact sigmoid < 0.05 (exclude safely);
        // borderline entries get the exact f64 gate in K2. (r6-r8-proven scheme)
        if (s > 0.0499999f) {
          unsigned key = __float_as_uint(s * ce[j % HW_]);   // base is a multiple of HW_
          int bin = (int)(key >> 16) - 0x3800;
          bin = bin < 0 ? 0 : (bin > NB - 1 ? NB - 1 : bin);
          atomicAdd(&hist[bin], 1u);
        }
      }
    }
    __syncthreads();
    unsigned* gh = ghist + ((size_t)n * KB + sb) * NB;
    for (int j = tid; j < NB; j += 1024) gh[j] = hist[j];
  } else if (b < N_ * KB + 140) {
    __shared__ float tile[4][32][33];
    int g = tid >> 8, sub = tid & 255;
    int tt = (b - N_ * KB) * 4 + g;             // 0..559
    int n = tt / 280, r = tt % 280, rqt = r / 7, ct = r % 7;
    int tx = sub & 31, ty = sub >> 5;           // 32x8
    int rq0 = rqt * 32, c0 = ct * 32;
    for (int i = 0; i < 4; ++i) {
      int cc = c0 + ty + i * 8, rq = rq0 + tx;
      if (cc < M2_) {
        float v = bm[((size_t)n * M2_ + cc) * HW_ + rq];
        tile[g][ty + i * 8][tx] = 1.f / (1.f + expf(-v));
      }
    }
    __syncthreads();
    for (int i = 0; i < 4; ++i) {
      int rq = rq0 + ty + i * 8, cc = c0 + tx;
      if (cc < M2_) msig[((size_t)n * HW_ + rq) * M2_ + cc] = tile[g][tx][ty + i * 8];
    }
  } else {
    int t = tid;
    if (t < H_) {
      int r = t; float acc = 0.f; wr[0 * H_ + r] = 0.f;
      for (int x = 0; x < IMH; ++x) {
        float src = ((float)x + 0.5f) * ((float)H_ / (float)IMH) - 0.5f;
        src = fminf(fmaxf(src, 0.f), (float)(H_ - 1));
        int i0 = (int)floorf(src); int i1 = min(i0 + 1, H_ - 1);
        float lam = src - (float)i0;
        float w = ((r == i0) ? (1.f - lam) : 0.f) + ((r == i1) ? lam : 0.f);
        acc += w; wr[(x + 1) * H_ + r] = acc;
      }
    } else if (t < H_ + W_) {
      int q = t - H_; float acc = 0.f; wc[0 * W_ + q] = 0.f;
      for (int y = 0; y < IMW; ++y) {
        float src = ((float)y + 0.5f) * ((float)W_ / (float)IMW) - 0.5f;
        src = fminf(fmaxf(src, 0.f), (float)(W_ - 1));
        int i0 = (int)floorf(src); int i1 = min(i0 + 1, W_ - 1);
        float lam = src - (float)i0;
        float w = ((q == i0) ? (1.f - lam) : 0.f) + ((q == i1) ? lam : 0.f);
        acc += w; wc[(y + 1) * W_ + q] = acc;
      }
    }
  }
}

// ---- K2: hist-reduce -> D,Dg -> latency-tolerant scan-compact -> exact f64 keys -> sort -> decode ----
struct SortSh { unsigned long long K[BCAP]; unsigned I[BCAP]; };

__global__ __launch_bounds__(1024) void k_seldec(const unsigned* ghist, const float* cls,
                                                 const float* cent, const float* loc, const float* breg,
                                                 double* bxd, double* scd, int* lab, int* vld, int* rg,
                                                 unsigned* keepg) {
  __shared__ SortSh sh;
  __shared__ float ce[HW_];
  __shared__ unsigned wtot[16], wabove[16];
  __shared__ unsigned sD, sG;
  int n = blockIdx.x, tid = threadIdx.x, lane = tid & 63, wid = tid >> 6;
  keepg[n * 1024 + tid] = 0;
  for (int j = tid; j < HW_; j += 1024) ce[j] = 1.f / (1.f + expf(-cent[n * HW_ + j]));
  // -- reduce 16 part-hists (uint2: bins 2tid, 2tid+1 adjacent); suffix scan (r5-proven) --
  const uint2* gh2 = (const uint2*)(ghist + (size_t)n * KB * NB);
  unsigned a = 0, bv = 0;
  #pragma unroll
  for (int q = 0; q < KB; ++q) { uint2 hv = gh2[q * (NB / 2) + tid]; a += hv.x; bv += hv.y; }
  if (tid == 0) sD = 0;
  unsigned s2 = a + bv, suf = s2;
  for (int off = 1; off < 64; off <<= 1) {
    unsigned v = __shfl_down(suf, off);
    if (lane + off < 64) suf += v;
  }
  if (lane == 0) wtot[wid] = suf;
  __syncthreads();
  if (tid == 0) { unsigned acc = 0; for (int w = 15; w >= 0; --w) { wabove[w] = acc; acc += wtot[w]; } }
  __syncthreads();
  unsigned above = (suf - s2) + wabove[wid];
  if (above < 1000u && above + bv >= 1000u) sD = (unsigned)(2 * tid + 1);
  if (above + bv < 1000u && above + bv + a >= 1000u) sD = (unsigned)(2 * tid);
  __syncthreads();
  unsigned D = sD;
  int Dg = (D > 0) ? (int)D - 1 : 0;            // guard bin covers f32-vs-f64 straddle (r6-proven)

  // -- latency-tolerant sweep: float4 loads, win flags into 128-bit register mask (no cross-lane) --
  unsigned wb[4] = {0u, 0u, 0u, 0u};            // 100 bits used
  {
    const float4* cb4 = (const float4*)(cls + (size_t)n * HWC_);
    #pragma unroll 5
    for (int it = 0; it < 25; ++it) {
      float4 v = cb4[it * 1024 + tid];
      int j0 = (it * 1024 + tid) * 4;
      float sv[4] = {v.x, v.y, v.z, v.w};
      #pragma unroll
      for (int kk = 0; kk < 4; ++kk) {
        float s = 1.f / (1.f + expf(-sv[kk]));
        bool win = false;
        if (s > 0.0499999f) {
          int j = j0 + kk;
          unsigned key = __float_as_uint(s * ce[j % HW_]);
          int bin = (int)(key >> 16) - 0x3800;
          bin = bin < 0 ? 0 : (bin > NB - 1 ? NB - 1 : bin);
          win = (bin >= Dg);
        }
        int bit = it * 4 + kk;
        if (win) wb[bit >> 5] |= (1u << (bit & 31));
      }
    }
  }
  // -- block exclusive scan of per-thread win counts (k_finish-proven pattern) --
  unsigned lc = (unsigned)(__popc(wb[0]) + __popc(wb[1]) + __popc(wb[2]) + __popc(wb[3]));
  unsigned pre = lc;
  for (int off = 1; off < 64; off <<= 1) {
    unsigned v = __shfl_up(pre, off);
    if (lane >= off) pre += v;
  }
  if (lane == 63) wtot[wid] = pre;              // reuse wtot/wabove (hist phase done)
  __syncthreads();
  if (tid == 0) { unsigned acc = 0; for (int w = 0; w < 16; ++w) { unsigned t2 = wtot[w]; wabove[w] = acc; acc += t2; } sG = acc; }
  __syncthreads();
  unsigned pos = wabove[wid] + pre - lc;        // exclusive base for this thread
  #pragma unroll
  for (int w2 = 0; w2 < 4; ++w2) {
    unsigned m = wb[w2];
    while (m) {
      int bit = __builtin_ctz(m); m &= m - 1;
      int b2 = w2 * 32 + bit;
      int j = ((b2 >> 2) * 1024 + tid) * 4 + (b2 & 3);
      if (pos < (unsigned)BCAP) sh.I[pos] = (unsigned)((j % HW_) * C_ + j / HW_);  // logical [HW,C]
      pos++;
    }
  }
  __syncthreads();
  int G = (int)sG; if (G > BCAP) G = BCAP;
  // -- exact f64 keys for winners only (r7/r8-proven numerics, matches np ref bitwise) --
  for (int p2 = tid; p2 < G; p2 += 1024) {
    unsigned idx = sh.I[p2];
    int hw = (int)(idx / C_), c = (int)(idx % C_);
    double aa = (double)cls[(size_t)n * HWC_ + (size_t)c * HW_ + hw];
    double ss = 1.0 / (1.0 + exp(-aa));
    double ced = 1.0 / (1.0 + exp(-(double)cent[n * HW_ + hw]));
    double v = (ss > 0.05) ? ss * ced : -1e9;
    sh.K[p2] = mapd(v);
  }
  int P = 1024; while (P < G) P <<= 1;
  for (int j = G + tid; j < P; j += 1024) { sh.K[j] = 0ull; sh.I[j] = 0xFFFFFFFFu; }
  __syncthreads();
  // -- bitonic sort by (key desc, idx asc): LDS rounds for stride>=64, shfl for <=32 (r5-proven) --
  int E = P >> 10;
  for (int sz = 2; sz <= P; sz <<= 1) {
    for (int st = sz >> 1; st >= 64; st >>= 1) {
      for (int p = tid; p < (P >> 1); p += 1024) {
        int i = ((p & ~(st - 1)) << 1) | (p & (st - 1));
        int j = i | st;
        bool up = ((i & sz) == 0);
        unsigned long long k1 = sh.K[i], k2 = sh.K[j];
        unsigned i1 = sh.I[i], i2 = sh.I[j];
        bool bef = (k1 > k2) || (k1 == k2 && i1 < i2);
        if (bef != up) { sh.K[i] = k2; sh.K[j] = k1; sh.I[i] = i2; sh.I[j] = i1; }
      }
      __syncthreads();
    }
    {
      int st0 = ((sz >> 1) < 32) ? (sz >> 1) : 32;
      for (int e = 0; e < E; ++e) {
        int elem = tid + (e << 10);
        unsigned long long k = sh.K[elem];
        unsigned ii = sh.I[elem];
        bool dir = ((elem & sz) == 0);
        for (int st = st0; st >= 1; st >>= 1) {
          unsigned long long ko = __shfl_xor(k, st);
          unsigned io = __shfl_xor(ii, st);
          bool low = ((elem & st) == 0);
          bool first = (k > ko) || (k == ko && ii < io);
          bool take_mine = first ^ (!low) ^ (!dir);
          if (!take_mine) { k = ko; ii = io; }
        }
        sh.K[elem] = k; sh.I[elem] = ii;
      }
      __syncthreads();
    }
  }
  // -- decode top-1000 (f64, exact vs np ref) -> per-candidate globals (verbatim r5/r8) --
  if (tid < KTOP) {
    unsigned long long key = sh.K[tid];
    unsigned idx = sh.I[tid];
    double v = unmapd(key);
    int valid = (v > -5e8) && (idx < (unsigned)HWC_);
    if (idx >= (unsigned)HWC_) idx = 0;
    int hw = (int)(idx / C_), c = (int)(idx % C_);
    double lx = (double)loc[hw * 2 + 0], ly = (double)loc[hw * 2 + 1];
    const float* rg4 = breg + (size_t)n * 4 * HW_;
    double r0 = (double)rg4[0 * HW_ + hw], r1 = (double)rg4[1 * HW_ + hw];
    double r2 = (double)rg4[2 * HW_ + hw], r3 = (double)rg4[3 * HW_ + hw];
    double b0 = lx - r0, b1 = ly - r1, b2 = lx + r2, b3 = ly + r3;
    double sc = valid ? sqrt(v) : 0.0;
    int bi0 = (int)b0, bi1 = (int)b1, bi2 = (int)b2, bi3 = (int)b3;
    int x1 = max(bi0, 0), x2 = min(bi2, IMH - 1), y1 = max(bi1, 0), y2 = min(bi3, IMW - 1);
    int rok = (x1 < x2) && (y1 < x2) && (y1 < y2);   // ref bug replicated
    int x1c = min(max(x1, 0), IMH), x2c = min(max(x2, 0), IMH);
    int y1c = min(max(y1, 0), IMW), y2c = min(max(y2, 0), IMW);
    int area = max((x2c - x1c) * (y2c - y1c), 1);
    double c0 = fmin(fmax(b0, 0.0), (double)(IMW - 1));
    double c1 = fmin(fmax(b1, 0.0), (double)(IMH - 1));
    double c2 = fmin(fmax(b2, 0.0), (double)(IMW - 1));
    double c3 = fmin(fmax(b3, 0.0), (double)(IMH - 1));
    size_t base = (size_t)n * 1024 + tid;
    bxd[base * 4 + 0] = c0; bxd[base * 4 + 1] = c1; bxd[base * 4 + 2] = c2; bxd[base * 4 + 3] = c3;
    scd[base] = sc; lab[base] = c + 1; vld[base] = valid;
    int* r8 = rg + base * 8;
    r8[0] = x1c; r8[1] = x2c; r8[2] = y1c; r8[3] = y2c; r8[4] = area; r8[5] = rok;
  }
}

// ---- K3: per-(image,class) greedy NMS (verbatim r5) ----
__global__ void k_nms(const double* bxd, const int* lab, const int* vld, unsigned* keepg) {
  int cls = blockIdx.x + 1, n = blockIdx.y, tid = threadIdx.x; // 64 threads = 1 wave
  __shared__ int mk[KTOP];
  __shared__ double mb0[KTOP], mb1[KTOP], mb2[KTOP], mb3[KTOP], ma[KTOP];
  __shared__ unsigned char kept[KTOP];
  int m = 0;
  for (int base = 0; base < KTOP; base += 64) {
    int t = base + tid;
    bool pred = (t < KTOP) && (lab[n * 1024 + t] == cls) && (vld[n * 1024 + t] != 0);
    unsigned long long bb = __ballot(pred);
    if (pred) {
      int pos = m + (int)__popcll(bb & ((1ull << tid) - 1ull));
      mk[pos] = t;
      const double* p = bxd + ((size_t)n * 1024 + t) * 4;
      double b0 = p[0], b1 = p[1], b2 = p[2], b3 = p[3];
      mb0[pos] = b0; mb1[pos] = b1; mb2[pos] = b2; mb3[pos] = b3;
      ma[pos] = (b2 - b0 + 1.0) * (b3 - b1 + 1.0);
      kept[pos] = 1;
    }
    m += (int)__popcll(bb);
  }
  __syncthreads();
  for (int i = 0; i < m; ++i) {
    if (kept[i]) {
      double x1 = mb0[i], y1 = mb1[i], x2 = mb2[i], y2 = mb3[i], ai = ma[i];
      for (int j = i + 1 + tid; j < m; j += 64) {
        double ltx = fmax(x1, mb0[j]), lty = fmax(y1, mb1[j]);
        double rbx = fmin(x2, mb2[j]), rby = fmin(y2, mb3[j]);
        double iw = fmax(rbx - ltx + 1.0, 0.0), ih = fmax(rby - lty + 1.0, 0.0);
        double inter = iw * ih;
        double uni = ai + ma[j] - inter;
        if (inter / fmax(uni, 1e-6) > 0.6) kept[j] = 0;
      }
    }
    __syncthreads();
  }
  for (int i = tid; i < m; i += 64) keepg[n * 1024 + mk[i]] = (unsigned)kept[i];
}

// ---- K4: fused stable partition + outputs + mask prob (verbatim r5) ----
__global__ __launch_bounds__(256) void k_finish(const unsigned* keepg, const double* bxd,
                                                const double* scd, const int* lab, const int* rg,
                                                const float* msig, const float* wr, const float* wc,
                                                float* out) {
  int t = blockIdx.x, n = blockIdx.y, tid = threadIdx.x, lane = tid & 63, wid = tid >> 6;
  __shared__ int lsel[100], lvf[100];
  __shared__ unsigned woff[4]; __shared__ unsigned sS;
  __shared__ float A[H_], B[W_];

  int i0 = tid * 4;
  unsigned ff[4]; int lc = 0;
  for (int j = 0; j < 4; ++j) {
    int i = i0 + j;
    ff[j] = (i < KTOP) ? keepg[n * 1024 + i] : 0u;
    lc += (int)ff[j];
  }
  unsigned pre = (unsigned)lc;
  for (int off = 1; off < 64; off <<= 1) {
    unsigned v = __shfl_up(pre, off);
    if (lane >= off) pre += v;
  }
  if (lane == 63) woff[wid] = pre;
  __syncthreads();
  if (tid == 0) { unsigned acc = 0; for (int w = 0; w < 4; ++w) { unsigned tmp = woff[w]; woff[w] = acc; acc += tmp; } sS = acc; }
  __syncthreads();
  int kpre = (int)(woff[wid] + pre - (unsigned)lc);
  int S = (int)sS;
  for (int j = 0; j < 4; ++j) {
    int i = i0 + j;
    if (i < KTOP) {
      if (ff[j]) { if (kpre < 100) { lsel[kpre] = i; lvf[kpre] = 1; } kpre++; }
      else { int slot = S + (i - kpre); if (slot < 100) { lsel[slot] = i; lvf[slot] = 0; } }
    }
  }
  __syncthreads();

  int k = lsel[t], vf = lvf[t];
  if (tid == 0) {
    const double* bb = bxd + ((size_t)n * 1024 + k) * 4;
    out[(n * 100 + t) * 4 + 0] = (float)bb[0];
    out[(n * 100 + t) * 4 + 1] = (float)bb[1];
    out[(n * 100 + t) * 4 + 2] = (float)bb[2];
    out[(n * 100 + t) * 4 + 3] = (float)bb[3];
    out[O_SC + n * 100 + t] = vf ? (float)scd[n * 1024 + k] : 0.f;
    out[O_LB + n * 100 + t] = (float)lab[n * 1024 + k];
    out[O_VF + n * 100 + t] = (float)vf;
  }
  const int* r8 = rg + ((size_t)n * 1024 + k) * 8;
  int x1c = r8[0], x2c = r8[1], y1c = r8[2], y2c = r8[3], area = r8[4], rok = r8[5];
  if (tid < H_) A[tid] = wr[x2c * H_ + tid] - wr[x1c * H_ + tid];
  else if (tid < H_ + W_) { int q = tid - H_; B[q] = wc[y2c * W_ + q] - wc[y1c * W_ + q]; }
  __syncthreads();
  if (tid < M2_) {
    float acc = 0.f;
    if (rok && vf) {
      int rlo = i0of(x1c, H_ - 1);
      int rhi = min(i0of(x2c - 1, H_ - 1) + 1, H_ - 1);
      int qlo = i0of(y1c, W_ - 1);
      int qhi = min(i0of(y2c - 1, W_ - 1) + 1, W_ - 1);
      for (int r = rlo; r <= rhi; ++r) {
        float ar = A[r];
        const float* mrow = msig + ((size_t)((n * H_ + r) * W_ + qlo)) * M2_ + tid;
        float rs = 0.f;
        #pragma unroll 4
        for (int q = qlo; q <= qhi; ++q) { rs += B[q] * mrow[0]; mrow += M2_; }
        acc += ar * rs;
      }
      acc /= (float)area;
    }
    out[O_PB + (size_t)(n * 100 + t) * M2_ + tid] = acc;
  }
}

extern "C" void kernel_launch(void* const* d_in, const int* in_sizes, int n_in,
                              void* d_out, int out_size, void* d_ws, size_t ws_size,
                              hipStream_t stream) {
  (void)in_sizes; (void)n_in; (void)out_size; (void)ws_size;
  const float* locations = (const float*)d_in[0];
  const float* box_cls   = (const float*)d_in[1];
  const float* box_reg   = (const float*)d_in[2];
  const float* cent      = (const float*)d_in[3];
  const float* box_mask  = (const float*)d_in[4];
  float* out = (float*)d_out;

  char* ws = (char*)d_ws;
  size_t off = 0;
  auto alloc = [&](size_t bytes) -> void* {
    void* p = ws + off;
    off = (off + bytes + 255) & ~(size_t)255;
    return p;
  };
  unsigned* ghist = (unsigned*)alloc((size_t)N_ * KB * NB * 4);
  double* bxd     = (double*)alloc((size_t)N_ * 1024 * 4 * 8);
  double* scd     = (double*)alloc((size_t)N_ * 1024 * 8);
  int* lab        = (int*)alloc((size_t)N_ * 1024 * 4);
  int* vld        = (int*)alloc((size_t)N_ * 1024 * 4);
  int* rg         = (int*)alloc((size_t)N_ * 1024 * 8 * 4);
  unsigned* keepg = (unsigned*)alloc((size_t)N_ * 1024 * 4);
  float* msig     = (float*)alloc((size_t)N_ * HW_ * M2_ * 4);
  float* wr       = (float*)alloc((size_t)(IMH + 1) * H_ * 4);
  float* wc       = (float*)alloc((size_t)(IMW + 1) * W_ * 4);

  k_pre<<<N_ * KB + 140 + 1, 1024, 0, stream>>>(box_cls, cent, box_mask, ghist, msig, wr, wc);
  k_seldec<<<N_, 1024, 0, stream>>>(ghist, box_cls, cent, locations, box_reg,
                                    bxd, scd, lab, vld, rg, keepg);
  k_nms<<<dim3(C_, N_), 64, 0, stream>>>(bxd, lab, vld, keepg);
  k_finish<<<dim3(100, N_), 256, 0, stream>>>(keepg, bxd, scd, lab, rg, msig, wr, wc, out);
}

// Round 10
// 97.524 us; speedup vs baseline: 1.8380x; 1.3158x over previous
//
#include <hip/hip_runtime.h>

#define DEVI __device__ __forceinline__

constexpr int N_ = 2, C_ = 80, H_ = 32, W_ = 40, HW_ = H_ * W_, HWC_ = HW_ * C_;
constexpr int KTOP = 1000, M2_ = 196;
constexpr int IMH = 256, IMW = 320;
constexpr int NB = 2048;          // f32-derived bins
constexpr int KB = 16;            // hist slices per image
constexpr int SLICE = HWC_ / KB;  // 6400
constexpr int BCAP = 2048;        // gathered-candidate cap (expected G ~ 1100)

// output layout (floats): bx[2][100][4] | sc[2][100] | lb[2][100] | prob[2][100][196] | vf[2][100]
constexpr int O_SC = 800, O_LB = 1000, O_PB = 1200, O_VF = 40400;
// conservative raw-logit floor: logit(0.05) = -2.9444389..., minus safety band
#define AFLOOR (-2.9446f)

DEVI unsigned long long mapd(double v) {
  unsigned long long u = (unsigned long long)__double_as_longlong(v);
  return (u & 0x8000000000000000ull) ? ~u : (u | 0x8000000000000000ull);
}
DEVI double unmapd(unsigned long long k) {
  unsigned long long u = (k & 0x8000000000000000ull) ? (k ^ 0x8000000000000000ull) : ~k;
  return __longlong_as_double((long long)u);
}
DEVI int i0of(int x, int cap) {  // exact first contributing mask row/col (matches table arithmetic)
  float src = ((float)x + 0.5f) * 0.125f - 0.5f;
  src = fminf(fmaxf(src, 0.f), (float)cap);
  return (int)floorf(src);
}

// ---- K1: per-slice f32 hist | mask transpose/sigmoid | weight tables (verbatim r9) ----
__global__ __launch_bounds__(1024) void k_pre(const float* cls, const float* cent, const float* bm,
                                              unsigned* ghist, float* msig, float* wr, float* wc) {
  int b = blockIdx.x, tid = threadIdx.x;
  if (b < N_ * KB) {
    __shared__ unsigned hist[NB];
    __shared__ float ce[HW_];
    int n = b >> 4, sb = b & 15;
    size_t base = (size_t)n * HWC_ + (size_t)sb * SLICE;
    for (int j = tid; j < NB; j += 1024) hist[j] = 0;
    for (int j = tid; j < HW_; j += 1024) ce[j] = 1.f / (1.f + expf(-cent[n * HW_ + j]));
    __syncthreads();
    #pragma unroll
    for (int it = 0; it < 7; ++it) {
      int j = it * 1024 + tid;
      if (j < SLICE) {
        float aa = cls[base + j];
        float s = 1.f / (1.f + expf(-aa));
        // conservative band: f32 s <= 0.0499999 implies exact sigmoid < 0.05 (exclude safely);
        // borderline entries get the exact f64 gate in K2. (r6-r9-proven scheme)
        if (s > 0.0499999f) {
          unsigned key = __float_as_uint(s * ce[j % HW_]);   // base is a multiple of HW_
          int bin = (int)(key >> 16) - 0x3800;
          bin = bin < 0 ? 0 : (bin > NB - 1 ? NB - 1 : bin);
          atomicAdd(&hist[bin], 1u);
        }
      }
    }
    __syncthreads();
    unsigned* gh = ghist + ((size_t)n * KB + sb) * NB;
    for (int j = tid; j < NB; j += 1024) gh[j] = hist[j];
  } else if (b < N_ * KB + 140) {
    __shared__ float tile[4][32][33];
    int g = tid >> 8, sub = tid & 255;
    int tt = (b - N_ * KB) * 4 + g;             // 0..559
    int n = tt / 280, r = tt % 280, rqt = r / 7, ct = r % 7;
    int tx = sub & 31, ty = sub >> 5;           // 32x8
    int rq0 = rqt * 32, c0 = ct * 32;
    for (int i = 0; i < 4; ++i) {
      int cc = c0 + ty + i * 8, rq = rq0 + tx;
      if (cc < M2_) {
        float v = bm[((size_t)n * M2_ + cc) * HW_ + rq];
        tile[g][ty + i * 8][tx] = 1.f / (1.f + expf(-v));
      }
    }
    __syncthreads();
    for (int i = 0; i < 4; ++i) {
      int rq = rq0 + ty + i * 8, cc = c0 + tx;
      if (cc < M2_) msig[((size_t)n * HW_ + rq) * M2_ + cc] = tile[g][tx][ty + i * 8];
    }
  } else {
    int t = tid;
    if (t < H_) {
      int r = t; float acc = 0.f; wr[0 * H_ + r] = 0.f;
      for (int x = 0; x < IMH; ++x) {
        float src = ((float)x + 0.5f) * ((float)H_ / (float)IMH) - 0.5f;
        src = fminf(fmaxf(src, 0.f), (float)(H_ - 1));
        int i0 = (int)floorf(src); int i1 = min(i0 + 1, H_ - 1);
        float lam = src - (float)i0;
        float w = ((r == i0) ? (1.f - lam) : 0.f) + ((r == i1) ? lam : 0.f);
        acc += w; wr[(x + 1) * H_ + r] = acc;
      }
    } else if (t < H_ + W_) {
      int q = t - H_; float acc = 0.f; wc[0 * W_ + q] = 0.f;
      for (int y = 0; y < IMW; ++y) {
        float src = ((float)y + 0.5f) * ((float)W_ / (float)IMW) - 0.5f;
        src = fminf(fmaxf(src, 0.f), (float)(W_ - 1));
        int i0 = (int)floorf(src); int i1 = min(i0 + 1, W_ - 1);
        float lam = src - (float)i0;
        float w = ((q == i0) ? (1.f - lam) : 0.f) + ((q == i1) ? lam : 0.f);
        acc += w; wc[(y + 1) * W_ + q] = acc;
      }
    }
  }
}

// ---- K2: hist-reduce -> D,Dg -> raw-logit sweep -> f64 keys -> exact-bin counting sort -> decode ----
struct SelSh {
  float ce[HW_];
  float athr[HW_];
  unsigned long long K[BCAP];
  unsigned I[BCAP];
  unsigned short eb[BCAP];
  unsigned short ord[BCAP];
  unsigned bh[NB];
  unsigned bs[NB];
  unsigned cur[NB];
  unsigned long long Ks[1024];
  unsigned Is[1024];
  unsigned wtot[16], wabove[16];
  unsigned sD, sG;
};

__global__ __launch_bounds__(1024) void k_seldec(const unsigned* ghist, const float* cls,
                                                 const float* cent, const float* loc, const float* breg,
                                                 double* bxd, double* scd, int* lab, int* vld, int* rg,
                                                 unsigned* keepg) {
  __shared__ SelSh sh;
  int n = blockIdx.x, tid = threadIdx.x, lane = tid & 63, wid = tid >> 6;
  keepg[n * 1024 + tid] = 0;
  for (int j = tid; j < HW_; j += 1024) sh.ce[j] = 1.f / (1.f + expf(-cent[n * HW_ + j]));
  // -- reduce 16 part-hists (uint2); suffix scan -> D (r9-proven snippet) --
  const uint2* gh2 = (const uint2*)(ghist + (size_t)n * KB * NB);
  unsigned a = 0, bv = 0;
  #pragma unroll
  for (int q = 0; q < KB; ++q) { uint2 hv = gh2[q * (NB / 2) + tid]; a += hv.x; bv += hv.y; }
  if (tid == 0) sh.sD = 0;
  unsigned s2 = a + bv, suf = s2;
  for (int off = 1; off < 64; off <<= 1) {
    unsigned v = __shfl_down(suf, off);
    if (lane + off < 64) suf += v;
  }
  if (lane == 0) sh.wtot[wid] = suf;
  __syncthreads();
  if (tid == 0) { unsigned acc = 0; for (int w = 15; w >= 0; --w) { sh.wabove[w] = acc; acc += sh.wtot[w]; } }
  __syncthreads();
  unsigned above = (suf - s2) + sh.wabove[wid];
  if (above < 1000u && above + bv >= 1000u) sh.sD = (unsigned)(2 * tid + 1);
  if (above + bv < 1000u && above + bv + a >= 1000u) sh.sD = (unsigned)(2 * tid);
  __syncthreads();
  unsigned D = sh.sD;
  int Dg = (D > 0) ? (int)D - 1 : 0;          // guard bin covers f32-vs-f64 straddle (r6-proven)

  // -- per-hw raw-logit gather threshold: a > athr[hw]  <=>  (conservatively) s32*ce >= keyThresh --
  float keyTh32 = __uint_as_float((unsigned)(Dg + 0x3800) << 16);  // lower bound of f32 key in bin Dg
  double keyTh = (double)keyTh32;
  for (int j = tid; j < HW_; j += 1024) {
    float af = AFLOOR;
    if (Dg > 0) {
      double slo = keyTh * (1.0 - 1e-6) / (double)sh.ce[j];   // conservative: catches all f32-bin>=Dg
      if (slo >= 0.999999) af = 1e30f;
      else if (slo > 0.05) {
        float ak = (float)(log(slo / (1.0 - slo)) - 2e-5);
        af = (ak > AFLOOR) ? ak : AFLOOR;
      }
    }
    sh.athr[j] = af;
  }
  for (int j = tid; j < NB; j += 1024) sh.bh[j] = 0;
  __syncthreads();

  // -- sweep: raw-logit compare only (float4 loads, 128-bit register win mask; r9 structure) --
  unsigned wb[4] = {0u, 0u, 0u, 0u};
  {
    const float4* cb4 = (const float4*)(cls + (size_t)n * HWC_);
    #pragma unroll 5
    for (int it = 0; it < 25; ++it) {
      float4 v = cb4[it * 1024 + tid];
      int j0 = (it * 1024 + tid) * 4;
      float sv[4] = {v.x, v.y, v.z, v.w};
      #pragma unroll
      for (int kk = 0; kk < 4; ++kk) {
        if (sv[kk] > sh.athr[(j0 + kk) % HW_]) {
          int bit = it * 4 + kk;
          wb[bit >> 5] |= (1u << (bit & 31));
        }
      }
    }
  }
  // -- block exclusive scan of per-thread win counts -> append positions (r9-proven) --
  unsigned lc = (unsigned)(__popc(wb[0]) + __popc(wb[1]) + __popc(wb[2]) + __popc(wb[3]));
  unsigned pre = lc;
  for (int off = 1; off < 64; off <<= 1) {
    unsigned v = __shfl_up(pre, off);
    if (lane >= off) pre += v;
  }
  if (lane == 63) sh.wtot[wid] = pre;
  __syncthreads();
  if (tid == 0) { unsigned acc = 0; for (int w = 0; w < 16; ++w) { unsigned t2 = sh.wtot[w]; sh.wabove[w] = acc; acc += t2; } sh.sG = acc; }
  __syncthreads();
  unsigned pos = sh.wabove[wid] + pre - lc;
  #pragma unroll
  for (int w2 = 0; w2 < 4; ++w2) {
    unsigned m = wb[w2];
    while (m) {
      int bit = __builtin_ctz(m); m &= m - 1;
      int b2 = w2 * 32 + bit;
      int j = ((b2 >> 2) * 1024 + tid) * 4 + (b2 & 3);
      if (pos < (unsigned)BCAP) sh.I[pos] = (unsigned)((j % HW_) * C_ + j / HW_);  // logical [HW,C]
      pos++;
    }
  }
  __syncthreads();
  int G = (int)sh.sG; if (G > BCAP) G = BCAP;

  // -- exact f64 keys + exact bin (from (float)(f64 key): monotone => bucket order exact) --
  for (int p = tid; p < G; p += 1024) {
    unsigned idx = sh.I[p];
    int hw = (int)(idx / C_), c = (int)(idx % C_);
    double aa = (double)cls[(size_t)n * HWC_ + (size_t)c * HW_ + hw];
    double ss = 1.0 / (1.0 + exp(-aa));
    double ced = 1.0 / (1.0 + exp(-(double)cent[n * HW_ + hw]));
    double v = (ss > 0.05) ? ss * ced : -1e9;   // exact reference gate
    sh.K[p] = mapd(v);
    int b = 0;
    if (v > 0.0) {
      unsigned kb = __float_as_uint((float)v);
      b = (int)(kb >> 16) - 0x3800;
      b = b < 0 ? 0 : (b > NB - 1 ? NB - 1 : b);
    }
    sh.eb[p] = (unsigned short)b;
    atomicAdd(&sh.bh[b], 1u);
  }
  __syncthreads();
  // -- suffix scan over gathered-set bucket hist -> bucket start offsets (descending-bin order) --
  {
    unsigned a2 = sh.bh[2 * tid], b2 = sh.bh[2 * tid + 1];
    unsigned s3 = a2 + b2, suf2 = s3;
    for (int off = 1; off < 64; off <<= 1) {
      unsigned v = __shfl_down(suf2, off);
      if (lane + off < 64) suf2 += v;
    }
    if (lane == 0) sh.wtot[wid] = suf2;
    __syncthreads();
    if (tid == 0) { unsigned acc = 0; for (int w = 15; w >= 0; --w) { sh.wabove[w] = acc; acc += sh.wtot[w]; } }
    __syncthreads();
    unsigned above2 = (suf2 - s3) + sh.wabove[wid];
    sh.bs[2 * tid + 1] = above2;        sh.bs[2 * tid] = above2 + b2;
    sh.cur[2 * tid + 1] = above2;       sh.cur[2 * tid] = above2 + b2;
  }
  __syncthreads();
  // -- scatter entry ids into buckets --
  for (int p = tid; p < G; p += 1024) {
    unsigned p2 = atomicAdd(&sh.cur[sh.eb[p]], 1u);
    sh.ord[p2] = (unsigned short)p;
  }
  __syncthreads();
  // -- exact rank within bucket (avg 1-2 mates) -> final placement; pad tail --
  for (int p = tid; p < G; p += 1024) {
    int b = sh.eb[p];
    unsigned lo = sh.bs[b], len = sh.bh[b];
    unsigned long long k1 = sh.K[p]; unsigned i1 = sh.I[p];
    unsigned r = lo;
    for (unsigned q = lo; q < lo + len; ++q) {
      int j = sh.ord[q];
      unsigned long long kj = sh.K[j]; unsigned ij = sh.I[j];
      if ((kj > k1) || (kj == k1 && ij < i1)) ++r;   // strict-before; self excluded naturally
    }
    if (r < 1024u) { sh.Ks[r] = k1; sh.Is[r] = i1; }
  }
  for (int j = G + tid; j < 1024; j += 1024) { sh.Ks[j] = 0ull; sh.Is[j] = 0xFFFFFFFFu; }
  __syncthreads();

  // -- decode top-1000 (f64, exact vs np ref) -> per-candidate globals (verbatim r9) --
  if (tid < KTOP) {
    unsigned long long key = sh.Ks[tid];
    unsigned idx = sh.Is[tid];
    double v = unmapd(key);
    int valid = (v > -5e8) && (idx < (unsigned)HWC_);
    if (idx >= (unsigned)HWC_) idx = 0;
    int hw = (int)(idx / C_), c = (int)(idx % C_);
    double lx = (double)loc[hw * 2 + 0], ly = (double)loc[hw * 2 + 1];
    const float* rg4 = breg + (size_t)n * 4 * HW_;
    double r0 = (double)rg4[0 * HW_ + hw], r1 = (double)rg4[1 * HW_ + hw];
    double r2 = (double)rg4[2 * HW_ + hw], r3 = (double)rg4[3 * HW_ + hw];
    double b0 = lx - r0, b1 = ly - r1, b2 = lx + r2, b3 = ly + r3;
    double sc = valid ? sqrt(v) : 0.0;
    int bi0 = (int)b0, bi1 = (int)b1, bi2 = (int)b2, bi3 = (int)b3;
    int x1 = max(bi0, 0), x2 = min(bi2, IMH - 1), y1 = max(bi1, 0), y2 = min(bi3, IMW - 1);
    int rok = (x1 < x2) && (y1 < x2) && (y1 < y2);   // ref bug replicated
    int x1c = min(max(x1, 0), IMH), x2c = min(max(x2, 0), IMH);
    int y1c = min(max(y1, 0), IMW), y2c = min(max(y2, 0), IMW);
    int area = max((x2c - x1c) * (y2c - y1c), 1);
    double c0 = fmin(fmax(b0, 0.0), (double)(IMW - 1));
    double c1 = fmin(fmax(b1, 0.0), (double)(IMH - 1));
    double c2 = fmin(fmax(b2, 0.0), (double)(IMW - 1));
    double c3 = fmin(fmax(b3, 0.0), (double)(IMH - 1));
    size_t base = (size_t)n * 1024 + tid;
    bxd[base * 4 + 0] = c0; bxd[base * 4 + 1] = c1; bxd[base * 4 + 2] = c2; bxd[base * 4 + 3] = c3;
    scd[base] = sc; lab[base] = c + 1; vld[base] = valid;
    int* r8 = rg + base * 8;
    r8[0] = x1c; r8[1] = x2c; r8[2] = y1c; r8[3] = y2c; r8[4] = area; r8[5] = rok;
  }
}

// ---- K3: per-(image,class) greedy NMS (verbatim r5) ----
__global__ void k_nms(const double* bxd, const int* lab, const int* vld, unsigned* keepg) {
  int cls = blockIdx.x + 1, n = blockIdx.y, tid = threadIdx.x; // 64 threads = 1 wave
  __shared__ int mk[KTOP];
  __shared__ double mb0[KTOP], mb1[KTOP], mb2[KTOP], mb3[KTOP], ma[KTOP];
  __shared__ unsigned char kept[KTOP];
  int m = 0;
  for (int base = 0; base < KTOP; base += 64) {
    int t = base + tid;
    bool pred = (t < KTOP) && (lab[n * 1024 + t] == cls) && (vld[n * 1024 + t] != 0);
    unsigned long long bb = __ballot(pred);
    if (pred) {
      int pos = m + (int)__popcll(bb & ((1ull << tid) - 1ull));
      mk[pos] = t;
      const double* p = bxd + ((size_t)n * 1024 + t) * 4;
      double b0 = p[0], b1 = p[1], b2 = p[2], b3 = p[3];
      mb0[pos] = b0; mb1[pos] = b1; mb2[pos] = b2; mb3[pos] = b3;
      ma[pos] = (b2 - b0 + 1.0) * (b3 - b1 + 1.0);
      kept[pos] = 1;
    }
    m += (int)__popcll(bb);
  }
  __syncthreads();
  for (int i = 0; i < m; ++i) {
    if (kept[i]) {
      double x1 = mb0[i], y1 = mb1[i], x2 = mb2[i], y2 = mb3[i], ai = ma[i];
      for (int j = i + 1 + tid; j < m; j += 64) {
        double ltx = fmax(x1, mb0[j]), lty = fmax(y1, mb1[j]);
        double rbx = fmin(x2, mb2[j]), rby = fmin(y2, mb3[j]);
        double iw = fmax(rbx - ltx + 1.0, 0.0), ih = fmax(rby - lty + 1.0, 0.0);
        double inter = iw * ih;
        double uni = ai + ma[j] - inter;
        if (inter / fmax(uni, 1e-6) > 0.6) kept[j] = 0;
      }
    }
    __syncthreads();
  }
  for (int i = tid; i < m; i += 64) keepg[n * 1024 + mk[i]] = (unsigned)kept[i];
}

// ---- K4: fused stable partition + outputs + mask prob (verbatim r5) ----
__global__ __launch_bounds__(256) void k_finish(const unsigned* keepg, const double* bxd,
                                                const double* scd, const int* lab, const int* rg,
                                                const float* msig, const float* wr, const float* wc,
                                                float* out) {
  int t = blockIdx.x, n = blockIdx.y, tid = threadIdx.x, lane = tid & 63, wid = tid >> 6;
  __shared__ int lsel[100], lvf[100];
  __shared__ unsigned woff[4]; __shared__ unsigned sS;
  __shared__ float A[H_], B[W_];

  int i0 = tid * 4;
  unsigned ff[4]; int lc = 0;
  for (int j = 0; j < 4; ++j) {
    int i = i0 + j;
    ff[j] = (i < KTOP) ? keepg[n * 1024 + i] : 0u;
    lc += (int)ff[j];
  }
  unsigned pre = (unsigned)lc;
  for (int off = 1; off < 64; off <<= 1) {
    unsigned v = __shfl_up(pre, off);
    if (lane >= off) pre += v;
  }
  if (lane == 63) woff[wid] = pre;
  __syncthreads();
  if (tid == 0) { unsigned acc = 0; for (int w = 0; w < 4; ++w) { unsigned tmp = woff[w]; woff[w] = acc; acc += tmp; } sS = acc; }
  __syncthreads();
  int kpre = (int)(woff[wid] + pre - (unsigned)lc);
  int S = (int)sS;
  for (int j = 0; j < 4; ++j) {
    int i = i0 + j;
    if (i < KTOP) {
      if (ff[j]) { if (kpre < 100) { lsel[kpre] = i; lvf[kpre] = 1; } kpre++; }
      else { int slot = S + (i - kpre); if (slot < 100) { lsel[slot] = i; lvf[slot] = 0; } }
    }
  }
  __syncthreads();

  int k = lsel[t], vf = lvf[t];
  if (tid == 0) {
    const double* bb = bxd + ((size_t)n * 1024 + k) * 4;
    out[(n * 100 + t) * 4 + 0] = (float)bb[0];
    out[(n * 100 + t) * 4 + 1] = (float)bb[1];
    out[(n * 100 + t) * 4 + 2] = (float)bb[2];
    out[(n * 100 + t) * 4 + 3] = (float)bb[3];
    out[O_SC + n * 100 + t] = vf ? (float)scd[n * 1024 + k] : 0.f;
    out[O_LB + n * 100 + t] = (float)lab[n * 1024 + k];
    out[O_VF + n * 100 + t] = (float)vf;
  }
  const int* r8 = rg + ((size_t)n * 1024 + k) * 8;
  int x1c = r8[0], x2c = r8[1], y1c = r8[2], y2c = r8[3], area = r8[4], rok = r8[5];
  if (tid < H_) A[tid] = wr[x2c * H_ + tid] - wr[x1c * H_ + tid];
  else if (tid < H_ + W_) { int q = tid - H_; B[q] = wc[y2c * W_ + q] - wc[y1c * W_ + q]; }
  __syncthreads();
  if (tid < M2_) {
    float acc = 0.f;
    if (rok && vf) {
      int rlo = i0of(x1c, H_ - 1);
      int rhi = min(i0of(x2c - 1, H_ - 1) + 1, H_ - 1);
      int qlo = i0of(y1c, W_ - 1);
      int qhi = min(i0of(y2c - 1, W_ - 1) + 1, W_ - 1);
      for (int r = rlo; r <= rhi; ++r) {
        float ar = A[r];
        const float* mrow = msig + ((size_t)((n * H_ + r) * W_ + qlo)) * M2_ + tid;
        float rs = 0.f;
        #pragma unroll 4
        for (int q = qlo; q <= qhi; ++q) { rs += B[q] * mrow[0]; mrow += M2_; }
        acc += ar * rs;
      }
      acc /= (float)area;
    }
    out[O_PB + (size_t)(n * 100 + t) * M2_ + tid] = acc;
  }
}

extern "C" void kernel_launch(void* const* d_in, const int* in_sizes, int n_in,
                              void* d_out, int out_size, void* d_ws, size_t ws_size,
                              hipStream_t stream) {
  (void)in_sizes; (void)n_in; (void)out_size; (void)ws_size;
  const float* locations = (const float*)d_in[0];
  const float* box_cls   = (const float*)d_in[1];
  const float* box_reg   = (const float*)d_in[2];
  const float* cent      = (const float*)d_in[3];
  const float* box_mask  = (const float*)d_in[4];
  float* out = (float*)d_out;

  char* ws = (char*)d_ws;
  size_t off = 0;
  auto alloc = [&](size_t bytes) -> void* {
    void* p = ws + off;
    off = (off + bytes + 255) & ~(size_t)255;
    return p;
  };
  unsigned* ghist = (unsigned*)alloc((size_t)N_ * KB * NB * 4);
  double* bxd     = (double*)alloc((size_t)N_ * 1024 * 4 * 8);
  double* scd     = (double*)alloc((size_t)N_ * 1024 * 8);
  int* lab        = (int*)alloc((size_t)N_ * 1024 * 4);
  int* vld        = (int*)alloc((size_t)N_ * 1024 * 4);
  int* rg         = (int*)alloc((size_t)N_ * 1024 * 8 * 4);
  unsigned* keepg = (unsigned*)alloc((size_t)N_ * 1024 * 4);
  float* msig     = (float*)alloc((size_t)N_ * HW_ * M2_ * 4);
  float* wr       = (float*)alloc((size_t)(IMH + 1) * H_ * 4);
  float* wc       = (float*)alloc((size_t)(IMW + 1) * W_ * 4);

  k_pre<<<N_ * KB + 140 + 1, 1024, 0, stream>>>(box_cls, cent, box_mask, ghist, msig, wr, wc);
  k_seldec<<<N_, 1024, 0, stream>>>(ghist, box_cls, cent, locations, box_reg,
                                    bxd, scd, lab, vld, rg, keepg);
  k_nms<<<dim3(C_, N_), 64, 0, stream>>>(bxd, lab, vld, keepg);
  k_finish<<<dim3(100, N_), 256, 0, stream>>>(keepg, bxd, scd, lab, rg, msig, wr, wc, out);
}